// Round 9
// baseline (47.117 us; speedup 1.0000x reference)
//
#include <hip/hip_runtime.h>

#define NPROLIF 12
#define NLIN 18
#define ROW 22                      // floats per element row
#define BLK 256
#define NSLAB 8192                  // B*T/BLK

#define AS1 __attribute__((address_space(1)))
#define AS3 __attribute__((address_space(3)))

// branchless 4-way select (wave-uniform index): v_cndmask chain
__device__ __forceinline__ float sel4(unsigned i, float x0, float x1, float x2, float x3) {
    float lo = (i & 1u) ? x1 : x0;
    float hi = (i & 1u) ? x3 : x2;
    return (i & 2u) ? hi : lo;
}

__global__ __launch_bounds__(BLK) void sindy_kernel(
    const float* __restrict__ cand,
    const float* __restrict__ a,
    const float* __restrict__ ss,
    const float* __restrict__ sgn,
    const float* __restrict__ K1p,
    const float* __restrict__ thetap,
    const float* __restrict__ K2p,
    const int* __restrict__ pidx,
    const int* __restrict__ lidx,
    const int* __restrict__ sprop,
    float* __restrict__ out)
{
    __shared__ float sRow[BLK*ROW];   // 22528 B: 4 wave-private 5632 B slices, linear
    __shared__ uint2 sPP[NPROLIF];    // per-BLOCK tables (built once, by wave 0)
    __shared__ uint4 sLP[NLIN];
    __shared__ float sScal[4];        // K1, invTheta, K2, coef0

    const int tid  = threadIdx.x;
    const int lane = tid & 63;
    const int wv   = tid >> 6;

    // ---- 1. every wave issues DMA for its OWN 64-row slice (7 loads, linear dest) ----
    const float* gw = cand + (size_t)blockIdx.x * (BLK*ROW) + wv * (64*ROW);
    float* lw = &sRow[wv * (64*ROW)];
    #pragma unroll
    for (int k = 0; k < 5; ++k)
        __builtin_amdgcn_global_load_lds((const AS1 void*)(gw + k*256 + lane*4),
                                         (AS3 void*)(lw + k*256), 16, 0, 0);
    #pragma unroll
    for (int j = 0; j < 2; ++j)
        __builtin_amdgcn_global_load_lds((const AS1 void*)(gw + 1280 + j*64 + lane),
                                         (AS3 void*)(lw + 1280 + j*64), 4, 0, 0);

    // ---- 2. per-BLOCK table build on wave 0 (lane-parallel vector loads),
    //         overlapped with all waves' DMA latency ----
    if (tid < NPROLIF) {
        int t = tid;
        int ia = pidx[t*3+0], ib = pidx[t*3+1], ic = pidx[t*3+2];
        unsigned avb  = __float_as_uint(a[1+t]);
        unsigned keep = ((sprop[1+t] != 0) ? 1u : 0u) ^ (avb >> 31);
        unsigned offs = (unsigned)ia | ((unsigned)ib << 2) | ((unsigned)(16 + ic*4) << 8);
        sPP[t] = make_uint2(offs, keep ? avb : 0u);
    } else if (tid < NPROLIF + NLIN) {           // tids 12..29
        int j = tid - NPROLIF;
        int i0 = lidx[j*2+0], i1 = lidx[j*2+1];
        unsigned avb  = __float_as_uint(a[1+NPROLIF+j]);
        unsigned keep = ((sprop[1+NPROLIF+j] != 0) ? 1u : 0u) ^ (avb >> 31);
        unsigned offs = (unsigned)i0 | ((unsigned)(16 + i1*4) << 8);
        unsigned A = 0x43fa0000u | (__float_as_uint(sgn[j]) & 0x80000000u);  // 500*sign
        sLP[j] = make_uint4(offs, keep ? avb : 0u, A, __float_as_uint(ss[i1]));
    } else if (tid == NPROLIF + NLIN) {          // tid 30
        unsigned avb  = __float_as_uint(a[0]);
        unsigned keep = ((sprop[0] != 0) ? 1u : 0u) ^ (avb >> 31);
        sScal[0] = K1p[0];
        sScal[1] = __builtin_amdgcn_rcpf(thetap[0]);   // theta=2 -> exact
        sScal[2] = K2p[0];
        sScal[3] = __uint_as_float(keep ? avb : 0u);
    }

    // ---- 3. RAW barrier: waits table ds_writes (lgkm) only — DMA stays in flight ----
    asm volatile("s_waitcnt lgkmcnt(0)" ::: "memory");
    __builtin_amdgcn_s_barrier();

    // ---- 4. per-wave drain: only THIS wave's 7 DMA loads (vmcnt is per-wave) ----
    asm volatile("s_waitcnt vmcnt(0)" ::: "memory");
    __builtin_amdgcn_sched_barrier(0);

    // ---- 5. compute from the wave-private slice + shared tables ----
    const char* row = (const char*)&sRow[tid*ROW];   // [con, x0,x1,x2, prot0..17]
    float con = sRow[tid*ROW+0];
    float x0  = sRow[tid*ROW+1];
    float x1  = sRow[tid*ROW+2];
    float x2  = sRow[tid*ROW+3];
    float xs  = x0 + x1 + x2;

    const float K1 = sScal[0], invTh = sScal[1], K2 = sScal[2];
    float acc = sScal[3] * con;                      // con term

    #pragma unroll
    for (int t = 0; t < NPROLIF; ++t) {
        uint2 pp = sPP[t];
        float coef = __uint_as_float(pp.y);
        float pA = sel4(pp.x & 3u, x0, x1, x2, xs);
        float pB = sel4((pp.x >> 2) & 3u, x0, x1, x2, xs);
        float pC = *(const float*)(row + ((pp.x >> 8) & 0xffu));   // LDS gather
        float h  = pC * __builtin_amdgcn_rcpf(K1 + pC);
        acc += coef * (pA * (1.0f - pB * invTh) * h);
    }

    #pragma unroll
    for (int t = 0; t < NLIN; ++t) {
        uint4 lp = sLP[t];
        float coef = __uint_as_float(lp.y);
        float A    = __uint_as_float(lp.z);          // 500*sign
        float ssv  = __uint_as_float(lp.w);
        float l0 = sel4(lp.x & 3u, x0, x1, x2, xs);
        float pr = *(const float*)(row + ((lp.x >> 8) & 0xffu));   // LDS gather
        float dp  = pr - ssv;
        float adp = fabsf(dp);
        float h   = adp * __builtin_amdgcn_rcpf(K2 + adp);
        float e   = __expf(-(A * dp - 25.0f));       // 500*(sign*dp - 0.05)
        float sig = __builtin_amdgcn_rcpf(1.0f + e);
        acc += coef * (l0 * h * sig);
    }

    out[(size_t)blockIdx.x * BLK + tid] = acc;
}

extern "C" void kernel_launch(void* const* d_in, const int* in_sizes, int n_in,
                              void* d_out, int out_size, void* d_ws, size_t ws_size,
                              hipStream_t stream) {
    const float* cand = (const float*)d_in[0];
    const float* a    = (const float*)d_in[1];
    const float* ss   = (const float*)d_in[2];
    const float* sgn  = (const float*)d_in[3];
    const float* K1   = (const float*)d_in[4];
    const float* th   = (const float*)d_in[5];
    const float* K2   = (const float*)d_in[6];
    const int*   pidx = (const int*)d_in[7];
    const int*   lidx = (const int*)d_in[8];
    const int*   sp   = (const int*)d_in[9];
    float* out = (float*)d_out;

    hipLaunchKernelGGL(sindy_kernel, dim3(NSLAB), dim3(BLK), 0, stream,
                       cand, a, ss, sgn, K1, th, K2, pidx, lidx, sp, out);
}

// Round 10
// 44.857 us; speedup vs baseline: 1.0504x; 1.0504x over previous
//
#include <hip/hip_runtime.h>

#define NPROLIF 12
#define NLIN 18
#define ROW 22                    // floats per element row
#define BLK 256                   // threads per block
#define F4_PER_BLK (BLK*ROW/4)    // 1408 float4 per block slab
#define NSLAB 8192                // B*T/BLK

#define AS1 __attribute__((address_space(1)))
#define AS3 __attribute__((address_space(3)))

// table layout in d_ws (uint32 words):
//  [0]=K1  [1]=invTheta  [2]=K2  [3]=coef0
//  [4+2t]   = prolif offs (ia | ib<<2 | protByteOff<<8),  [5+2t] = masked coef   (t<12)
//  [28+4j]  = lin offs (i0 | protByteOff<<8), [29+4j]=coef, [30+4j]=500*sign, [31+4j]=ss[i1]  (j<18)

__global__ void build_tables(const float* __restrict__ a,
                             const float* __restrict__ ss,
                             const float* __restrict__ sgn,
                             const float* __restrict__ K1p,
                             const float* __restrict__ thetap,
                             const float* __restrict__ K2p,
                             const int* __restrict__ pidx,
                             const int* __restrict__ lidx,
                             const int* __restrict__ sprop,
                             unsigned* __restrict__ tw)
{
    const int t = threadIdx.x;
    if (t == 0) {
        tw[0] = __float_as_uint(K1p[0]);
        tw[1] = __float_as_uint(__builtin_amdgcn_rcpf(thetap[0]));  // theta=2 -> exact
        tw[2] = __float_as_uint(K2p[0]);
        unsigned avb  = __float_as_uint(a[0]);
        unsigned keep = ((sprop[0] != 0) ? 1u : 0u) ^ (avb >> 31);
        tw[3] = keep ? avb : 0u;
    } else if (t <= NPROLIF) {                    // t = 1..12 -> prolif term t-1
        int i = t - 1;
        int ia = pidx[i*3+0], ib = pidx[i*3+1], ic = pidx[i*3+2];
        unsigned avb  = __float_as_uint(a[1+i]);
        unsigned keep = ((sprop[1+i] != 0) ? 1u : 0u) ^ (avb >> 31);
        tw[4+2*i] = (unsigned)ia | ((unsigned)ib << 2) | ((unsigned)(16 + ic*4) << 8);
        tw[5+2*i] = keep ? avb : 0u;
    } else if (t <= NPROLIF + NLIN) {             // t = 13..30 -> lin term t-13
        int j = t - 1 - NPROLIF;
        int i0 = lidx[j*2+0], i1 = lidx[j*2+1];
        unsigned avb  = __float_as_uint(a[1+NPROLIF+j]);
        unsigned keep = ((sprop[1+NPROLIF+j] != 0) ? 1u : 0u) ^ (avb >> 31);
        tw[28+4*j] = (unsigned)i0 | ((unsigned)(16 + i1*4) << 8);
        tw[29+4*j] = keep ? avb : 0u;
        tw[30+4*j] = 0x43fa0000u | (__float_as_uint(sgn[j]) & 0x80000000u);  // 500*sign
        tw[31+4*j] = __float_as_uint(ss[i1]);
    }
}

// branchless 4-way select (scalar index): cndmask chain
__device__ __forceinline__ float sel4(unsigned i, float x0, float x1, float x2, float x3) {
    float lo = (i & 1u) ? x1 : x0;
    float hi = (i & 1u) ? x3 : x2;
    return (i & 2u) ? hi : lo;
}

__global__ __launch_bounds__(BLK) void sindy_kernel(
    const float* __restrict__ cand,
    const unsigned* __restrict__ tw,   // packed tables in d_ws: uniform -> s_load
    float* __restrict__ out)
{
    __shared__ float sRow[BLK*ROW];   // 22528 B: raw 22-float rows, linear (DMA dest)

    const int tid = threadIdx.x;
    const int wbase = tid & ~63;      // lane-0 tid of this wave (wave-uniform LDS base)

    // ---- global->LDS DMA staging (R3-proven) ----
    const float4* g4 = reinterpret_cast<const float4*>(cand)
                       + (long long)blockIdx.x * F4_PER_BLK;
    float4* s4 = reinterpret_cast<float4*>(sRow);
    #pragma unroll
    for (int k = 0; k < 5; ++k) {
        __builtin_amdgcn_global_load_lds(
            (const AS1 void*)(g4 + k*BLK + tid),
            (AS3 void*)(s4 + k*BLK + wbase), 16, 0, 0);
    }
    if (tid < F4_PER_BLK - 5*BLK) {   // last 128 float4s
        __builtin_amdgcn_global_load_lds(
            (const AS1 void*)(g4 + 5*BLK + tid),
            (AS3 void*)(s4 + 5*BLK + wbase), 16, 0, 0);
    }

    __syncthreads();   // drains vmcnt (DMA)

    // ---- header ----
    const char* row = (const char*)&sRow[tid*ROW];   // [con, x0,x1,x2, prot0..17]
    float con = sRow[tid*ROW+0];
    float x0  = sRow[tid*ROW+1];
    float x1  = sRow[tid*ROW+2];
    float x2  = sRow[tid*ROW+3];
    float xs  = x0 + x1 + x2;

    // scalar-cache constants (uniform addresses -> s_load, zero LDS traffic)
    const float K1    = __uint_as_float(tw[0]);
    const float invTh = __uint_as_float(tw[1]);
    const float K2    = __uint_as_float(tw[2]);
    float acc = __uint_as_float(tw[3]) * con;        // con term

    #pragma unroll
    for (int t = 0; t < NPROLIF; ++t) {
        unsigned offs = tw[4+2*t];                   // s_load
        float coef = __uint_as_float(tw[5+2*t]);     // s_load
        float pA = sel4(offs & 3u, x0, x1, x2, xs);
        float pB = sel4((offs >> 2) & 3u, x0, x1, x2, xs);
        float pC = *(const float*)(row + ((offs >> 8) & 0xffu));   // LDS gather
        float h  = pC * __builtin_amdgcn_rcpf(K1 + pC);
        acc += coef * (pA * (1.0f - pB * invTh) * h);
    }

    #pragma unroll
    for (int t = 0; t < NLIN; ++t) {
        unsigned offs = tw[28+4*t];                  // s_load
        float coef = __uint_as_float(tw[29+4*t]);
        float A    = __uint_as_float(tw[30+4*t]);    // 500*sign
        float ssv  = __uint_as_float(tw[31+4*t]);
        float l0 = sel4(offs & 3u, x0, x1, x2, xs);
        float pr = *(const float*)(row + ((offs >> 8) & 0xffu));   // LDS gather
        float dp  = pr - ssv;
        float adp = fabsf(dp);
        float h   = adp * __builtin_amdgcn_rcpf(K2 + adp);
        float e   = __expf(-(A * dp - 25.0f));       // 500*(sign*dp - 0.05)
        float sig = __builtin_amdgcn_rcpf(1.0f + e);
        acc += coef * (l0 * h * sig);
    }

    out[(long long)blockIdx.x * BLK + tid] = acc;
}

extern "C" void kernel_launch(void* const* d_in, const int* in_sizes, int n_in,
                              void* d_out, int out_size, void* d_ws, size_t ws_size,
                              hipStream_t stream) {
    const float* cand = (const float*)d_in[0];
    const float* a    = (const float*)d_in[1];
    const float* ss   = (const float*)d_in[2];
    const float* sgn  = (const float*)d_in[3];
    const float* K1   = (const float*)d_in[4];
    const float* th   = (const float*)d_in[5];
    const float* K2   = (const float*)d_in[6];
    const int*   pidx = (const int*)d_in[7];
    const int*   lidx = (const int*)d_in[8];
    const int*   sp   = (const int*)d_in[9];
    unsigned* tw = (unsigned*)d_ws;      // 100 dwords used
    float* out = (float*)d_out;

    hipLaunchKernelGGL(build_tables, dim3(1), dim3(64), 0, stream,
                       a, ss, sgn, K1, th, K2, pidx, lidx, sp, tw);
    hipLaunchKernelGGL(sindy_kernel, dim3(NSLAB), dim3(BLK), 0, stream,
                       cand, tw, out);
}